// Round 1
// 692.691 us; speedup vs baseline: 1.0423x; 1.0423x over previous
//
#include <hip/hip_runtime.h>

// ---------------------------------------------------------------------------
// OHEM cross-entropy, 4 kernels, zero global atomics:
//   1) loss_hist_k: loss[i] = log(sum exp(pred[i,:])) - pred[i,target[i]],
//      binned (linear, [0,16), width 1/256) into a per-block LDS histogram
//      (u32 cnt + f32 sum), flushed by plain stores to a private slab.
//      1024 threads/block: 32 KB LDS x 2 blocks/CU = 32 waves/CU (100% occ).
//   2) reduce1_k: 256 blocks (16 bin-chunks x 16 slab-chunks) -> 16 partials
//      per bin. Uses all CUs instead of 16.
//   3) reduce2_k: fold 16 partials -> cnt[4096], dsum[4096].
//   4) scan_k: suffix-scan from the top, pivot bin, mean of top k via
//      exact sums above pivot + r * (pivot bin average).
// ---------------------------------------------------------------------------

#define NB 4096
#define G  512
#define CH 16            // slab chunks in reduce1
#define SPC (G / CH)     // 32 slabs per chunk
#define SCALE 256.0f

__global__ __launch_bounds__(1024, 8) void loss_hist_k(const float* __restrict__ pred,
                                                       const int* __restrict__ target,
                                                       unsigned* __restrict__ priv_cnt,
                                                       float* __restrict__ priv_sum,
                                                       int N) {
    __shared__ unsigned hc[NB];
    __shared__ float    hs[NB];
    int t = threadIdx.x;
    for (int i = t; i < NB; i += 1024) { hc[i] = 0u; hs[i] = 0.0f; }
    __syncthreads();

    int gtid = blockIdx.x * 1024 + t;
    int wave = gtid >> 6;
    int lane = t & 63;
    int g4   = lane >> 4;              // which row of the quad (16 lanes per row)
    int l16  = lane & 15;
    int nw   = (gridDim.x * 1024) >> 6; // total waves

    for (int r = wave * 8; r < N; r += nw * 8) {
        // clamp rows so all lanes stay active for shuffles; commit is guarded
        int rowA = r + g4;       if (rowA > N - 1) rowA = N - 1;
        int rowB = r + 4 + g4;   if (rowB > N - 1) rowB = N - 1;
        const float4* pa = (const float4*)(pred + (size_t)rowA * 128);
        const float4* pb = (const float4*)(pred + (size_t)rowB * 128);
        float4 a1 = pa[l16], a2 = pa[l16 + 16];   // cols l16*4..+3, 64+l16*4..+3
        float4 b1 = pb[l16], b2 = pb[l16 + 16];
        int ta = target[rowA], tb = target[rowB];

        float ea = __expf(a1.x) + __expf(a1.y) + __expf(a1.z) + __expf(a1.w)
                 + __expf(a2.x) + __expf(a2.y) + __expf(a2.z) + __expf(a2.w);
        float eb = __expf(b1.x) + __expf(b1.y) + __expf(b1.z) + __expf(b1.w)
                 + __expf(b2.x) + __expf(b2.y) + __expf(b2.z) + __expf(b2.w);
        #pragma unroll
        for (int off = 1; off < 16; off <<= 1) {
            ea += __shfl_xor(ea, off);
            eb += __shfl_xor(eb, off);
        }
        // fetch pred[row, target[row]]: owner lane (ta>>2)&15 in this 16-group
        float4 sa = (ta & 64) ? a2 : a1;
        float xsa = (ta & 2) ? ((ta & 1) ? sa.w : sa.z)
                             : ((ta & 1) ? sa.y : sa.x);
        float xta = __shfl(xsa, (lane & 48) + ((ta >> 2) & 15));
        float4 sb = (tb & 64) ? b2 : b1;
        float xsb = (tb & 2) ? ((tb & 1) ? sb.w : sb.z)
                             : ((tb & 1) ? sb.y : sb.x);
        float xtb = __shfl(xsb, (lane & 48) + ((tb >> 2) & 15));

        if (l16 == 0) {
            float la = fmaxf(__logf(ea) - xta, 0.0f);
            float lb = fmaxf(__logf(eb) - xtb, 0.0f);
            if (r + g4 < N) {
                int ba = min((int)(la * SCALE), NB - 1);
                atomicAdd(&hc[ba], 1u);
                atomicAdd(&hs[ba], la);
            }
            if (r + 4 + g4 < N) {
                int bb = min((int)(lb * SCALE), NB - 1);
                atomicAdd(&hc[bb], 1u);
                atomicAdd(&hs[bb], lb);
            }
        }
    }
    __syncthreads();
    unsigned base = blockIdx.x * NB;
    for (int i = t; i < NB; i += 1024) {
        priv_cnt[base + i] = hc[i];
        priv_sum[base + i] = hs[i];
    }
}

__global__ __launch_bounds__(256) void reduce1_k(const unsigned* __restrict__ priv_cnt,
                                                 const float* __restrict__ priv_sum,
                                                 unsigned* __restrict__ pcnt,
                                                 double* __restrict__ psum) {
    int bc = blockIdx.x & 15;           // 16 bin chunks x 256 bins
    int sc = blockIdx.x >> 4;           // CH slab chunks x SPC slabs
    int bin = bc * 256 + threadIdx.x;
    int g0 = sc * SPC;
    unsigned c = 0;
    double s = 0.0;
    #pragma unroll 4
    for (int g = g0; g < g0 + SPC; g++) {
        c += priv_cnt[(size_t)g * NB + bin];
        s += (double)priv_sum[(size_t)g * NB + bin];
    }
    pcnt[(size_t)sc * NB + bin] = c;
    psum[(size_t)sc * NB + bin] = s;
}

__global__ __launch_bounds__(256) void reduce2_k(const unsigned* __restrict__ pcnt,
                                                 const double* __restrict__ psum,
                                                 unsigned* __restrict__ cnt,
                                                 double* __restrict__ dsum) {
    int bin = blockIdx.x * 256 + threadIdx.x;   // 16 blocks x 256 = 4096 bins
    unsigned c = 0;
    double s = 0.0;
    #pragma unroll
    for (int k = 0; k < CH; k++) {
        c += pcnt[(size_t)k * NB + bin];
        s += psum[(size_t)k * NB + bin];
    }
    cnt[bin] = c;
    dsum[bin] = s;
}

__global__ __launch_bounds__(256) void scan_k(const unsigned* __restrict__ cnt,
                                              const double* __restrict__ dsum,
                                              float* __restrict__ out, int K) {
    __shared__ unsigned sc[256];
    __shared__ double   ss[256];
    __shared__ int      pivot;
    __shared__ unsigned above_c;
    __shared__ double   above_s;
    int t = threadIdx.x;
    unsigned c = 0;
    double s = 0.0;
    #pragma unroll
    for (int j = 0; j < 16; j++) { c += cnt[t * 16 + j]; s += dsum[t * 16 + j]; }
    sc[t] = c;
    ss[t] = s;
    __syncthreads();
    #pragma unroll
    for (int step = 1; step < 256; step <<= 1) {
        unsigned vc = (t + step < 256) ? sc[t + step] : 0u;
        double   vs = (t + step < 256) ? ss[t + step] : 0.0;
        __syncthreads();
        sc[t] += vc;
        ss[t] += vs;
        __syncthreads();
    }
    unsigned incl = sc[t];
    unsigned abv  = (t < 255) ? sc[t + 1] : 0u;
    if (incl >= (unsigned)K && abv < (unsigned)K) {
        pivot   = t;
        above_c = abv;
        above_s = (t < 255) ? ss[t + 1] : 0.0;
    }
    __syncthreads();
    if (t == 0) {
        int pc = pivot;
        unsigned acc = above_c;
        double  accs = above_s;
        for (int b = 15; b >= 0; b--) {
            unsigned cb = cnt[pc * 16 + b];
            if (acc + cb >= (unsigned)K) {
                unsigned rIn = (unsigned)K - acc;
                double   avg = dsum[pc * 16 + b] / (double)cb;
                out[0] = (float)((accs + (double)rIn * avg) / (double)K);
                return;
            }
            acc  += cb;
            accs += dsum[pc * 16 + b];
        }
    }
}

extern "C" void kernel_launch(void* const* d_in, const int* in_sizes, int n_in,
                              void* d_out, int out_size, void* d_ws, size_t ws_size,
                              hipStream_t stream) {
    const float* pred   = (const float*)d_in[0];
    const int*   target = (const int*)d_in[1];
    int N = in_sizes[1];                    // pred is [N,128]
    int K = (int)((double)N * 0.7);         // matches python int(N*0.7)

    char* ws = (char*)d_ws;
    unsigned* priv_cnt = (unsigned*)ws;                                  // 8 MB
    float*    priv_sum = (float*)(ws + (size_t)G * NB * 4);              // 8 MB
    unsigned* pcnt     = (unsigned*)(ws + (size_t)2 * G * NB * 4);       // 256 KB
    double*   psum     = (double*)(ws + (size_t)2 * G * NB * 4
                                      + (size_t)CH * NB * 4);            // 512 KB
    unsigned* cnt      = (unsigned*)((char*)psum + (size_t)CH * NB * 8); // 16 KB
    double*   dsum     = (double*)((char*)cnt + (size_t)NB * 4);         // 32 KB

    loss_hist_k<<<G, 1024, 0, stream>>>(pred, target, priv_cnt, priv_sum, N);
    reduce1_k<<<CH * 16, 256, 0, stream>>>(priv_cnt, priv_sum, pcnt, psum);
    reduce2_k<<<NB / 256, 256, 0, stream>>>(pcnt, psum, cnt, dsum);
    scan_k<<<1, 256, 0, stream>>>(cnt, dsum, (float*)d_out, K);
}